// Round 7
// baseline (1183.118 us; speedup 1.0000x reference)
//
#include <hip/hip_runtime.h>
#include <math.h>

#define D_ 256
#define KSLOT 32
#define BSH 5          // 32 rows per bucket
#define CAP 1280       // bucket capacity (expected ~977, ~10 sigma margin)
typedef unsigned short ushort_t;
typedef __attribute__((ext_vector_type(8))) short bf16x8;
typedef __attribute__((ext_vector_type(4))) float f32x4;

// ---------- helpers ----------
__device__ __forceinline__ float softplus_f(float x){
  return (x > 20.0f) ? x : log1pf(expf(x));
}
__device__ __forceinline__ float bflo(unsigned u){ return __uint_as_float(u << 16); }
__device__ __forceinline__ float bfhi(unsigned u){ return __uint_as_float(u & 0xFFFF0000u); }
__device__ __forceinline__ ushort_t f2b(float f){
  unsigned u = __float_as_uint(f);
  unsigned r = u + 0x7FFFu + ((u >> 16) & 1u);
  return (ushort_t)(r >> 16);
}
__device__ __forceinline__ unsigned pack2(float a, float b){
  return (unsigned)f2b(a) | ((unsigned)f2b(b) << 16);
}
__device__ __forceinline__ void unpack16(uint4 a, uint4 b, float* f){
  f[0]=bflo(a.x); f[1]=bfhi(a.x); f[2]=bflo(a.y); f[3]=bfhi(a.y);
  f[4]=bflo(a.z); f[5]=bfhi(a.z); f[6]=bflo(a.w); f[7]=bfhi(a.w);
  f[8]=bflo(b.x); f[9]=bfhi(b.x); f[10]=bflo(b.y); f[11]=bfhi(b.y);
  f[12]=bflo(b.z); f[13]=bfhi(b.z); f[14]=bflo(b.w); f[15]=bfhi(b.w);
}
__device__ __forceinline__ float block_reduce_sum(float v, float* sbuf){
  #pragma unroll
  for (int o = 32; o > 0; o >>= 1) v += __shfl_xor(v, o);
  int t = threadIdx.x, wid = t >> 6, lane = t & 63;
  if (lane == 0) sbuf[wid] = v;
  __syncthreads();
  if (t == 0) sbuf[0] = sbuf[0] + sbuf[1] + sbuf[2] + sbuf[3];
  __syncthreads();
  float r = sbuf[0];
  __syncthreads();
  return r;
}

// ---------- zero fill ----------
__global__ __launch_bounds__(256) void zerok(float4* __restrict__ p, size_t n4){
  float4 z; z.x = z.y = z.z = z.w = 0.f;
  for (size_t i = (size_t)blockIdx.x * 256 + threadIdx.x; i < n4; i += (size_t)gridDim.x * 256)
    p[i] = z;
}

// ---------- layernorm forward -> bf16 G ----------
__global__ __launch_bounds__(256) void ln_fwd(const float* __restrict__ X, const float* __restrict__ gamma,
    const float* __restrict__ beta, ushort_t* __restrict__ Gb, float* __restrict__ mean, float* __restrict__ rstd)
{
  __shared__ float sbuf[8];
  int n = blockIdx.x, t = threadIdx.x;
  size_t idx = (size_t)n * D_ + t;
  float x = X[idx];
  float mu = block_reduce_sum(x, sbuf) * (1.0f / D_);
  float d = x - mu;
  float var = block_reduce_sum(d * d, sbuf) * (1.0f / D_);
  float rs = rsqrtf(var + 1e-5f);
  Gb[idx] = f2b(d * rs * gamma[t] + beta[t]);
  if (t == 0){ mean[n] = mu; rstd[n] = rs; }
}

// ---------- fused weight prep ----------
__global__ __launch_bounds__(256) void wprep_all(const float* __restrict__ W_Q2, const float* __restrict__ W_K2,
    const float* __restrict__ W_Q3, const float* __restrict__ W_K3, const float* __restrict__ W_Qm,
    ushort_t* __restrict__ WtQm, ushort_t* __restrict__ WtF2, ushort_t* __restrict__ WtF3,
    ushort_t* __restrict__ WbQm, ushort_t* __restrict__ Bt2, ushort_t* __restrict__ Bt3)
{
  int idx = blockIdx.x * 256 + threadIdx.x;
  if (idx < 65536){
    int m = idx >> 8, k = idx & 255;
    WtQm[idx] = f2b(W_Qm[k * 256 + m]);
    return;
  }
  idx -= 65536;
  if (idx < 131072){
    int m = idx >> 8, k = idx & 255;
    WtF2[idx] = f2b(m < 256 ? W_Q2[k * 256 + m] : W_K2[k * 256 + (m - 256)]);
    return;
  }
  idx -= 131072;
  if (idx < 262144){
    int m = idx >> 8, k = idx & 255;
    WtF3[idx] = f2b(m < 512 ? W_Q3[k * 512 + m] : W_K3[k * 512 + (m - 512)]);
    return;
  }
  idx -= 262144;
  if (idx < 65536){ WbQm[idx] = f2b(W_Qm[idx]); return; }
  idx -= 65536;
  if (idx < 131072){
    int d = idx >> 9, k = idx & 511;
    Bt2[idx] = f2b(k < 256 ? W_Q2[d * 256 + k] : W_K2[d * 256 + (k - 256)]);
    return;
  }
  idx -= 131072;
  if (idx < 262144){
    int d = idx >> 10, k = idx & 1023;
    Bt3[idx] = f2b(k < 512 ? W_Q3[d * 512 + k] : W_K3[d * 512 + (k - 512)]);
  }
}

// ---------- MFMA GEMM: C[N,M] op= A[N,K] @ Bt[M,K]^T ----------
template<int OUT_MODE>  // 0 store fp32, 1 accumulate fp32, 2 store bf16
__global__ __launch_bounds__(256) void gemm_bt_mfma(const ushort_t* __restrict__ A,
    const ushort_t* __restrict__ Bt, void* __restrict__ C, int K, int M)
{
  __shared__ __align__(16) ushort_t As[128 * 32];
  __shared__ __align__(16) ushort_t Bs[128 * 32];
  int t = threadIdx.x;
  int wave = t >> 6, lane = t & 63;
  int row0 = blockIdx.y * 128;
  int col0 = blockIdx.x * 128;
  int wrow = (wave & 1) * 64;
  int wcol = (wave >> 1) * 64;
  f32x4 acc[4][4];
  #pragma unroll
  for (int i = 0; i < 4; ++i)
    #pragma unroll
    for (int j = 0; j < 4; ++j)
      acc[i][j] = (f32x4){0.f, 0.f, 0.f, 0.f};
  int srow = t >> 1;
  int soff = (t & 1) * 16;
  const ushort_t* Ag = A + (size_t)(row0 + srow) * K + soff;
  const ushort_t* Bg = Bt + (size_t)(col0 + srow) * K + soff;
  ushort_t* Al = As + srow * 32 + soff;
  ushort_t* Bl = Bs + srow * 32 + soff;
  int lrow = lane & 15, lk = (lane >> 4) * 8;
  for (int k0 = 0; k0 < K; k0 += 32){
    uint4 av0 = *(const uint4*)(Ag + k0);
    uint4 av1 = *(const uint4*)(Ag + k0 + 8);
    uint4 bv0 = *(const uint4*)(Bg + k0);
    uint4 bv1 = *(const uint4*)(Bg + k0 + 8);
    __syncthreads();
    *(uint4*)Al = av0; *(uint4*)(Al + 8) = av1;
    *(uint4*)Bl = bv0; *(uint4*)(Bl + 8) = bv1;
    __syncthreads();
    bf16x8 af[4], bf_[4];
    #pragma unroll
    for (int i = 0; i < 4; ++i)
      af[i] = *(const bf16x8*)(As + (wrow + i * 16 + lrow) * 32 + lk);
    #pragma unroll
    for (int j = 0; j < 4; ++j)
      bf_[j] = *(const bf16x8*)(Bs + (wcol + j * 16 + lrow) * 32 + lk);
    #pragma unroll
    for (int i = 0; i < 4; ++i)
      #pragma unroll
      for (int j = 0; j < 4; ++j)
        acc[i][j] = __builtin_amdgcn_mfma_f32_16x16x32_bf16(af[i], bf_[j], acc[i][j], 0, 0, 0);
  }
  int rbase = row0 + wrow + (lane >> 4) * 4;
  int cbase = col0 + wcol + (lane & 15);
  #pragma unroll
  for (int i = 0; i < 4; ++i){
    #pragma unroll
    for (int r = 0; r < 4; ++r){
      size_t rowoff = (size_t)(rbase + i * 16 + r) * M;
      #pragma unroll
      for (int j = 0; j < 4; ++j){
        int col = cbase + j * 16;
        float v = acc[i][j][r];
        if (OUT_MODE == 0)      ((float*)C)[rowoff + col] = v;
        else if (OUT_MODE == 1) ((float*)C)[rowoff + col] += v;
        else                    ((ushort_t*)C)[rowoff + col] = f2b(v);
      }
    }
  }
}

// ---------- Km = B_mem @ W_Km -> bf16 padded [128,256] (rows >=32 zeroed here) ----------
__global__ __launch_bounds__(256) void km_kernel(const float* __restrict__ Bm, const float* __restrict__ W,
    ushort_t* __restrict__ Kmb)
{
  __shared__ float sb[D_];
  int k = blockIdx.x, t = threadIdx.x;
  if (k < KSLOT){
    sb[t] = Bm[(size_t)k * D_ + t];
    __syncthreads();
    float acc = 0.f;
    for (int d = 0; d < D_; ++d) acc += sb[d] * W[(size_t)d * D_ + t];
    Kmb[(size_t)k * D_ + t] = f2b(acc);
  } else {
    Kmb[(size_t)k * D_ + t] = 0;
  }
}

// ---------- mem softmax: Sm[N,128] fp32 (cols 0..31 valid) -> P' bf16 [N,128] + lse ----------
__global__ __launch_bounds__(256) void softmax32(const float* __restrict__ Sm, ushort_t* __restrict__ Pb,
    float* __restrict__ lseM, const float* __restrict__ bmp, const float* __restrict__ lmp)
{
  int t = threadIdx.x;
  int r = blockIdx.x * 8 + (t >> 5);
  int lane = t & 31;
  float bs = fminf(softplus_f(*bmp), 5.0f) * 0.0625f;
  float coef = -softplus_f(*lmp) * 0.0625f;
  float s = Sm[(size_t)r * 128 + lane] * bs;
  float m = s;
  #pragma unroll
  for (int o = 16; o > 0; o >>= 1) m = fmaxf(m, __shfl_xor(m, o, 32));
  float e = expf(s - m);
  float se = e;
  #pragma unroll
  for (int o = 16; o > 0; o >>= 1) se += __shfl_xor(se, o, 32);
  ushort_t* dst = Pb + (size_t)r * 128 + lane;
  dst[0] = f2b(coef * e / se);
  dst[32] = 0; dst[64] = 0; dst[96] = 0;
  if (lane == 0) lseM[r] = m + logf(se);
}

// ---------- order-2 CSR: Pass A (bucket binning) ----------
__global__ __launch_bounds__(256) void passA2(const int* __restrict__ c2, const int* __restrict__ u2,
    int* __restrict__ bcntC, int* __restrict__ bcntU, unsigned* __restrict__ pairC,
    uint2* __restrict__ pairU, int NE_)
{
  int e = blockIdx.x * 256 + threadIdx.x;
  if (e >= NE_) return;
  int c = c2[e], u = u2[e];
  int bc = c >> BSH, bu = u >> BSH;
  int sc = atomicAdd(bcntC + bc, 1);
  unsigned gsc = (unsigned)bc * CAP + (unsigned)sc;
  bool okc = (sc < CAP);
  if (okc) pairC[gsc] = (unsigned)(c & 31) | ((unsigned)u << 5);
  int su = atomicAdd(bcntU + bu, 1);
  if (su < CAP && okc){
    uint2 pu; pu.x = (unsigned)(u & 31) | ((unsigned)c << 5); pu.y = gsc;
    pairU[(size_t)bu * CAP + su] = pu;
  }
}

// ---------- mixed exclusive scans: block0 bcntC->bbaseC, block1 bcntU->bbaseU, block2/3 cur3 in place ----------
__global__ __launch_bounds__(256) void scan_mixed(const int* __restrict__ bcntC, int* __restrict__ bbaseC,
    const int* __restrict__ bcntU, int* __restrict__ bbaseU, int* __restrict__ cur3, int NBK, int N_)
{
  __shared__ int wsum[4];
  __shared__ int carry;
  const int* src; int* dst; int n;
  if (blockIdx.x == 0){ src = bcntC; dst = bbaseC; n = NBK; }
  else if (blockIdx.x == 1){ src = bcntU; dst = bbaseU; n = NBK; }
  else if (blockIdx.x == 2){ src = cur3; dst = cur3; n = N_; }
  else { src = cur3 + N_; dst = cur3 + N_; n = N_; }
  int t = threadIdx.x, lane = t & 63, wid = t >> 6;
  if (t == 0) carry = 0;
  __syncthreads();
  for (int base = 0; base < n; base += 256){
    int v = src[base + t];
    int x = v;
    #pragma unroll
    for (int o = 1; o < 64; o <<= 1){
      int y = __shfl_up(x, o);
      if (lane >= o) x += y;
    }
    if (lane == 63) wsum[wid] = x;
    __syncthreads();
    int woff = 0;
    for (int i = 0; i < wid; ++i) woff += wsum[i];
    int excl = carry + woff + x - v;
    dst[base + t] = excl;
    __syncthreads();
    if (t == 255) carry = carry + woff + x;
    __syncthreads();
  }
}

// ---------- order-2 CSR: Pass B (place bucket entries into CSR, emit row offsets) ----------
// SIDE 0: pairC (4B entries, gslot implicit) -> adjc{u,gslot}, curc2 ends
// SIDE 1: pairU (8B entries with gslot)      -> adju{c,gslot}, curu2 ends
template<int SIDE>
__global__ __launch_bounds__(256) void passB2(const int* __restrict__ bcnt, const int* __restrict__ bbase,
    const unsigned* __restrict__ pairC, const uint2* __restrict__ pairU,
    uint2* __restrict__ adj, int* __restrict__ rowEnd)
{
  __shared__ int lcnt[32];
  __shared__ int lcur[32];
  int b = blockIdx.x, t = threadIdx.x;
  int cnt = bcnt[b]; if (cnt > CAP) cnt = CAP;
  int base = bbase[b];
  if (t < 32) lcnt[t] = 0;
  __syncthreads();
  for (int i = t; i < cnt; i += 256){
    unsigned key = SIDE ? pairU[(size_t)b * CAP + i].x : pairC[(size_t)b * CAP + i];
    atomicAdd(&lcnt[key & 31], 1);
  }
  __syncthreads();
  if (t < 32){
    int x = lcnt[t];
    #pragma unroll
    for (int o = 1; o < 32; o <<= 1){
      int y = __shfl_up(x, o);
      if (t >= o) x += y;
    }
    lcur[t] = base + x - lcnt[t];
    rowEnd[(b << BSH) + t] = base + x;
  }
  __syncthreads();
  for (int i = t; i < cnt; i += 256){
    unsigned other, gslot;
    unsigned key;
    if (SIDE){
      uint2 ent = pairU[(size_t)b * CAP + i];
      key = ent.x; other = ent.x >> 5; gslot = ent.y;
    } else {
      key = pairC[(size_t)b * CAP + i];
      other = key >> 5; gslot = (unsigned)b * CAP + i;
    }
    int pos = atomicAdd(&lcur[key & 31], 1);
    uint2 o2; o2.x = other; o2.y = gslot;
    adj[pos] = o2;
  }
}

// ---------- order-3 CSR build (small, keep old scheme) ----------
__global__ __launch_bounds__(256) void hist3(const int* __restrict__ c3, const int* __restrict__ u3,
    const int* __restrict__ v3, int* __restrict__ cnt_c, int* __restrict__ cnt_i, int NT_)
{
  int e = blockIdx.x * 256 + threadIdx.x;
  if (e >= NT_) return;
  atomicAdd(cnt_c + c3[e], 1);
  atomicAdd(cnt_i + u3[e], 1);
  atomicAdd(cnt_i + v3[e], 1);
}
__global__ __launch_bounds__(256) void scatter3(const int* __restrict__ c3, const int* __restrict__ u3,
    const int* __restrict__ v3, const int* __restrict__ tt, int* __restrict__ cur_c, int* __restrict__ cur_i,
    unsigned* __restrict__ adj3c, uint2* __restrict__ adj3i, int NT_)
{
  int e = blockIdx.x * 256 + threadIdx.x;
  if (e >= NT_) return;
  int c = c3[e], u = u3[e], v = v3[e], tau = tt[e];
  int pc = atomicAdd(cur_c + c, 1);
  adj3c[pc] = (unsigned)u | ((unsigned)v << 15) | ((unsigned)tau << 30);
  int pu = atomicAdd(cur_i + u, 1);
  uint2 eu; eu.x = (unsigned)c | ((unsigned)tau << 15) | ((unsigned)v << 16); eu.y = (unsigned)pc;
  adj3i[pu] = eu;
  int pv = atomicAdd(cur_i + v, 1);
  uint2 ev; ev.x = (unsigned)c | ((unsigned)tau << 15) | ((unsigned)u << 16); ev.y = (unsigned)pc;
  adj3i[pv] = ev;
}

// ---------- order-2 by-c: 16 lanes/edge, online softmax + dQ2 ----------
__global__ __launch_bounds__(256) void e2_rowc(const ushort_t* __restrict__ QK2, const int* __restrict__ rowEnd,
    const uint2* __restrict__ adjc, ushort_t* __restrict__ dstage, float* __restrict__ s2e,
    float2* __restrict__ ml2, const float* __restrict__ b2p, const float* __restrict__ l2p)
{
  int wave = threadIdx.x >> 6, lane = threadIdx.x & 63;
  int r = blockIdx.x * 4 + wave;
  int quarter = lane >> 4, sub = lane & 15;
  float b2s = fminf(softplus_f(*b2p), 5.0f) * 0.0625f;
  float lam2 = softplus_f(*l2p);
  int start = (r > 0) ? rowEnd[r - 1] : 0;
  int end = rowEnd[r];
  const ushort_t* qrow = QK2 + (size_t)r * 512 + sub * 16;
  float qf[16];
  unpack16(*(const uint4*)qrow, *(const uint4*)(qrow + 8), qf);
  float m = -1e30f, l = 0.f;
  float a[16] = {};
  for (int p = start + quarter; p < end; p += 4){
    uint2 ent = adjc[p];
    int u = (int)ent.x;
    const ushort_t* krow = QK2 + (size_t)u * 512 + 256 + sub * 16;
    float kf[16];
    unpack16(*(const uint4*)krow, *(const uint4*)(krow + 8), kf);
    float d = 0.f;
    #pragma unroll
    for (int j = 0; j < 16; ++j) d += qf[j] * kf[j];
    d += __shfl_xor(d, 1); d += __shfl_xor(d, 2); d += __shfl_xor(d, 4); d += __shfl_xor(d, 8);
    float s = d * b2s;
    if (sub == 0) s2e[ent.y] = s;
    float mn = fmaxf(m, s);
    float sc = expf(m - mn);
    float pt = expf(s - mn);
    l = l * sc + pt;
    #pragma unroll
    for (int j = 0; j < 16; ++j) a[j] = a[j] * sc + pt * kf[j];
    m = mn;
  }
  float M = fmaxf(m, __shfl_xor(m, 16)); M = fmaxf(M, __shfl_xor(M, 32));
  float scq = expf(m - M);
  float L = l * scq;
  L += __shfl_xor(L, 16); L += __shfl_xor(L, 32);
  #pragma unroll
  for (int j = 0; j < 16; ++j){
    float x = a[j] * scq;
    x += __shfl_xor(x, 16); x += __shfl_xor(x, 32);
    a[j] = x;
  }
  float linv = 0.f, coef = 0.f;
  if (end > start){ linv = 1.0f / L; coef = -lam2 * 0.0625f * linv; }
  if (lane == 0){
    float2 ml; ml.x = M; ml.y = linv;
    ml2[r] = ml;
  }
  if (quarter == 0){
    ushort_t* dst = dstage + (size_t)r * 512 + sub * 16;
    uint4 p0, p1;
    p0.x = pack2(coef*a[0], coef*a[1]);   p0.y = pack2(coef*a[2], coef*a[3]);
    p0.z = pack2(coef*a[4], coef*a[5]);   p0.w = pack2(coef*a[6], coef*a[7]);
    p1.x = pack2(coef*a[8], coef*a[9]);   p1.y = pack2(coef*a[10], coef*a[11]);
    p1.z = pack2(coef*a[12], coef*a[13]); p1.w = pack2(coef*a[14], coef*a[15]);
    *(uint4*)dst = p0; *(uint4*)(dst + 8) = p1;
  }
}

// ---------- order-2 by-u: stored scores via gslot, dK2 ----------
__global__ __launch_bounds__(256) void e2_rowu(const ushort_t* __restrict__ QK2, const int* __restrict__ rowEnd,
    const uint2* __restrict__ adju, const float* __restrict__ s2e, const float2* __restrict__ ml2,
    ushort_t* __restrict__ dstage, const float* __restrict__ l2p)
{
  int wave = threadIdx.x >> 6, lane = threadIdx.x & 63;
  int r = blockIdx.x * 4 + wave;
  int quarter = lane >> 4, sub = lane & 15;
  float lam2 = softplus_f(*l2p);
  int start = (r > 0) ? rowEnd[r - 1] : 0;
  int end = rowEnd[r];
  float a[16] = {};
  for (int p = start + quarter; p < end; p += 4){
    uint2 ent = adju[p];
    int c = (int)ent.x;
    float2 ml = ml2[c];
    float pe = expf(s2e[ent.y] - ml.x) * ml.y;
    const ushort_t* qrow = QK2 + (size_t)c * 512 + sub * 16;
    float qf[16];
    unpack16(*(const uint4*)qrow, *(const uint4*)(qrow + 8), qf);
    #pragma unroll
    for (int j = 0; j < 16; ++j) a[j] += pe * qf[j];
  }
  #pragma unroll
  for (int j = 0; j < 16; ++j){
    float x = a[j];
    x += __shfl_xor(x, 16); x += __shfl_xor(x, 32);
    a[j] = x;
  }
  float coef = -lam2 * 0.0625f;
  if (quarter == 0){
    ushort_t* dst = dstage + (size_t)r * 512 + 256 + sub * 16;
    uint4 p0, p1;
    p0.x = pack2(coef*a[0], coef*a[1]);   p0.y = pack2(coef*a[2], coef*a[3]);
    p0.z = pack2(coef*a[4], coef*a[5]);   p0.w = pack2(coef*a[6], coef*a[7]);
    p1.x = pack2(coef*a[8], coef*a[9]);   p1.y = pack2(coef*a[10], coef*a[11]);
    p1.z = pack2(coef*a[12], coef*a[13]); p1.w = pack2(coef*a[14], coef*a[15]);
    *(uint4*)dst = p0; *(uint4*)(dst + 8) = p1;
  }
}

// ---------- order-3 by-c: online softmax + dQ3, wave per row, T in LDS ----------
__global__ __launch_bounds__(256) void e3_rowc(const ushort_t* __restrict__ QK3, const float* __restrict__ Tt,
    const int* __restrict__ cur_c, const unsigned* __restrict__ adj3c, ushort_t* __restrict__ dstage,
    float* __restrict__ s3c, float2* __restrict__ ml3, const float* __restrict__ b3p,
    const float* __restrict__ l3p)
{
  __shared__ float sT[1024];
  int wave = threadIdx.x >> 6, lane = threadIdx.x & 63;
  int r = blockIdx.x * 4 + wave;
  for (int i = threadIdx.x; i < 1024; i += 256) sT[i] = Tt[i];
  __syncthreads();
  float b3s = fminf(softplus_f(*b3p), 5.0f) * 0.0625f;
  float lam3 = softplus_f(*l3p);
  int start = (r > 0) ? cur_c[r - 1] : 0;
  int end = cur_c[r];
  uint4 qw = *(const uint4*)(QK3 + (size_t)r * 1024 + lane * 8);
  float q[8] = {bflo(qw.x),bfhi(qw.x),bflo(qw.y),bfhi(qw.y),bflo(qw.z),bfhi(qw.z),bflo(qw.w),bfhi(qw.w)};
  float T0[8], T1[8];
  #pragma unroll
  for (int j = 0; j < 8; ++j){ T0[j] = sT[lane * 8 + j]; T1[j] = sT[512 + lane * 8 + j]; }
  float m = -1e30f, l = 0.f;
  float a[8] = {};
  for (int p = start; p < end; ++p){
    unsigned ent = adj3c[p];
    int u = ent & 32767, v = (ent >> 15) & 32767, tau = (ent >> 30) & 1;
    uint4 bw = *(const uint4*)(QK3 + (size_t)u * 1024 + 512 + lane * 8);
    uint4 cw = *(const uint4*)(QK3 + (size_t)v * 1024 + 512 + lane * 8);
    float kb[8] = {bflo(bw.x),bfhi(bw.x),bflo(bw.y),bfhi(bw.y),bflo(bw.z),bfhi(bw.z),bflo(bw.w),bfhi(bw.w)};
    float kc[8] = {bflo(cw.x),bfhi(cw.x),bflo(cw.y),bfhi(cw.y),bflo(cw.z),bfhi(cw.z),bflo(cw.w),bfhi(cw.w)};
    float prod[8];
    float d = 0.f;
    #pragma unroll
    for (int j = 0; j < 8; ++j){
      float tj = tau ? T1[j] : T0[j];
      prod[j] = kb[j] * kc[j] * tj;
      d += q[j] * prod[j];
    }
    #pragma unroll
    for (int o = 32; o > 0; o >>= 1) d += __shfl_xor(d, o);
    float s = d * b3s;
    if (lane == 0) s3c[p] = s;
    float mn = fmaxf(m, s);
    float sc = expf(m - mn);
    float pt = expf(s - mn);
    l = l * sc + pt;
    #pragma unroll
    for (int j = 0; j < 8; ++j) a[j] = a[j]*sc + pt*prod[j];
    m = mn;
  }
  float linv = 0.f, coef = 0.f;
  if (end > start){ linv = 1.0f / l; coef = -lam3 * 0.0625f * linv; }
  uint4 o4;
  o4.x = pack2(coef*a[0], coef*a[1]); o4.y = pack2(coef*a[2], coef*a[3]);
  o4.z = pack2(coef*a[4], coef*a[5]); o4.w = pack2(coef*a[6], coef*a[7]);
  *(uint4*)(dstage + (size_t)r * 1024 + lane * 8) = o4;
  if (lane == 0){
    float2 ml; ml.x = m; ml.y = linv;
    ml3[r] = ml;
  }
}

// ---------- order-3 incidence: stored scores, dK3, T in LDS ----------
__global__ __launch_bounds__(256) void e3_rowi(const ushort_t* __restrict__ QK3, const float* __restrict__ Tt,
    const int* __restrict__ cur_i, const uint2* __restrict__ adj3i, const float* __restrict__ s3c,
    const float2* __restrict__ ml3, ushort_t* __restrict__ dstage, const float* __restrict__ l3p)
{
  __shared__ float sT[1024];
  int wave = threadIdx.x >> 6, lane = threadIdx.x & 63;
  int r = blockIdx.x * 4 + wave;
  for (int i = threadIdx.x; i < 1024; i += 256) sT[i] = Tt[i];
  __syncthreads();
  float lam3 = softplus_f(*l3p);
  int start = (r > 0) ? cur_i[r - 1] : 0;
  int end = cur_i[r];
  float T0[8], T1[8];
  #pragma unroll
  for (int j = 0; j < 8; ++j){ T0[j] = sT[lane * 8 + j]; T1[j] = sT[512 + lane * 8 + j]; }
  float a[8] = {};
  for (int p = start; p < end; ++p){
    uint2 ent = adj3i[p];
    int c = ent.x & 32767, tau = (ent.x >> 15) & 1, other = (ent.x >> 16) & 32767;
    float2 ml = ml3[c];
    float pe = expf(s3c[ent.y] - ml.x) * ml.y;
    uint4 qw = *(const uint4*)(QK3 + (size_t)c * 1024 + lane * 8);
    uint4 ow = *(const uint4*)(QK3 + (size_t)other * 1024 + 512 + lane * 8);
    float q[8] = {bflo(qw.x),bfhi(qw.x),bflo(qw.y),bfhi(qw.y),bflo(qw.z),bfhi(qw.z),bflo(qw.w),bfhi(qw.w)};
    float ko[8] = {bflo(ow.x),bfhi(ow.x),bflo(ow.y),bfhi(ow.y),bflo(ow.z),bfhi(ow.z),bflo(ow.w),bfhi(ow.w)};
    #pragma unroll
    for (int j = 0; j < 8; ++j){
      float tj = tau ? T1[j] : T0[j];
      a[j] += pe * q[j] * ko[j] * tj;
    }
  }
  float coef = -lam3 * 0.0625f;
  uint4 o4;
  o4.x = pack2(coef*a[0], coef*a[1]); o4.y = pack2(coef*a[2], coef*a[3]);
  o4.z = pack2(coef*a[4], coef*a[5]); o4.w = pack2(coef*a[6], coef*a[7]);
  *(uint4*)(dstage + (size_t)r * 1024 + 512 + lane * 8) = o4;
}

// ---------- LN backward + clips + update ----------
__global__ __launch_bounds__(256) void ln_bwd_update(const float* __restrict__ X, const float* __restrict__ dG,
    const float* __restrict__ gamma, const float* __restrict__ mean, const float* __restrict__ rstd,
    const float* __restrict__ step_p, float* __restrict__ out)
{
  __shared__ float sbuf[8];
  int n = blockIdx.x, t = threadIdx.x;
  size_t idx = (size_t)n * D_ + t;
  float x = X[idx];
  float rs = rstd[n];
  float xh = (x - mean[n]) * rs;
  float dxh = dG[idx] * gamma[t];
  float s1 = block_reduce_sum(dxh, sbuf) * (1.0f / D_);
  float s2v = block_reduce_sum(dxh * xh, sbuf) * (1.0f / D_);
  float dx = rs * (dxh - s1 - xh * s2v);
  float gn2 = block_reduce_sum(dx * dx, sbuf);
  float gn = fmaxf(sqrtf(gn2), 1e-6f);
  float gsc = fminf(1.0f / gn, 1.0f);
  float stp = step_p[0] * 0.9999f;
  float xn = x - stp * gsc * dx;
  float sn2 = block_reduce_sum(xn * xn, sbuf);
  float sn = fmaxf(sqrtf(sn2), 1e-6f);
  float ssc = fminf(10.0f / sn, 1.0f);
  out[idx] = xn * ssc;
}

// ---------- single-block: all three energy sums + final combine ----------
__global__ __launch_bounds__(256) void energy_final(const float2* __restrict__ ml2, const float2* __restrict__ ml3,
    const float* __restrict__ lseM, int n, const float* l2p, const float* l3p, const float* lmp,
    const float* b2p, const float* b3p, const float* bmp, float* __restrict__ outE)
{
  __shared__ float sbuf[8];
  int t = threadIdx.x;
  float a2 = 0.f, a3 = 0.f, am = 0.f;
  for (int i = t; i < n; i += 256){
    float2 v2 = ml2[i];
    if (v2.y > 0.f) a2 += v2.x - logf(v2.y);
    float2 v3 = ml3[i];
    if (v3.y > 0.f) a3 += v3.x - logf(v3.y);
    am += lseM[i];
  }
  float s2 = block_reduce_sum(a2, sbuf);
  float s3 = block_reduce_sum(a3, sbuf);
  float sm = block_reduce_sum(am, sbuf);
  if (t == 0){
    float l2 = softplus_f(*l2p), l3 = softplus_f(*l3p), lm = softplus_f(*lmp);
    float b2 = fminf(softplus_f(*b2p), 5.0f);
    float b3 = fminf(softplus_f(*b3p), 5.0f);
    float bm = fminf(softplus_f(*bmp), 5.0f);
    *outE = -(l2 / b2) * s2 - (l3 / b3) * s3 - (lm / bm) * sm;
  }
}

static inline void zfill(void* p, size_t nElems, hipStream_t stream){
  size_t n4 = nElems / 4;
  int blocks = (int)(((n4 + 255) / 256) < 16384 ? ((n4 + 255) / 256) : 16384);
  if (blocks < 1) blocks = 1;
  zerok<<<blocks, 256, 0, stream>>>((float4*)p, n4);
}

extern "C" void kernel_launch(void* const* d_in, const int* in_sizes, int n_in,
                              void* d_out, int out_size, void* d_ws, size_t ws_size,
                              hipStream_t stream)
{
  const float* X     = (const float*)d_in[0];
  const int*   c2    = (const int*)d_in[1];
  const int*   u2    = (const int*)d_in[2];
  const int*   c3    = (const int*)d_in[3];
  const int*   u3    = (const int*)d_in[4];
  const int*   v3    = (const int*)d_in[5];
  const int*   tt    = (const int*)d_in[6];
  const float* stepp = (const float*)d_in[7];
  const float* gamma = (const float*)d_in[8];
  const float* beta  = (const float*)d_in[9];
  const float* W_Q2  = (const float*)d_in[10];
  const float* W_K2  = (const float*)d_in[11];
  const float* W_Q3  = (const float*)d_in[12];
  const float* W_K3  = (const float*)d_in[13];
  const float* T_tau = (const float*)d_in[14];
  const float* W_Qm  = (const float*)d_in[15];
  const float* W_Km  = (const float*)d_in[16];
  const float* B_mem = (const float*)d_in[17];
  const float* l2p   = (const float*)d_in[18];
  const float* l3p   = (const float*)d_in[19];
  const float* lmp   = (const float*)d_in[20];
  const float* b2p   = (const float*)d_in[21];
  const float* b3p   = (const float*)d_in[22];
  const float* bmp   = (const float*)d_in[23];

  const int N  = in_sizes[0] / D_;
  const int NE = in_sizes[1];
  const int NT = in_sizes[3];
  const int NBK = N >> BSH;
  const size_t ND = (size_t)N * D_;

  // ---- byte arena ----
  char* base = (char*)d_ws;
  size_t off = 0;
  auto alloc = [&](size_t bytes) -> void* {
    void* p = base + off;
    off += (bytes + 255) & ~(size_t)255;
    return p;
  };
  ushort_t* Gb    = (ushort_t*)alloc(ND * 2);            // 16 MB
  ushort_t* bufA  = (ushort_t*)alloc(ND * 4 * 2);        // 64 MB
  ushort_t* bufB  = (ushort_t*)alloc(ND * 4 * 2);        // 64 MB
  int*      zreg  = (int*)     alloc(((size_t)2 * N + 2 * NBK) * 4); // curc3|curi3|bcntC|bcntU
  int*      bbaseC= (int*)     alloc((size_t)NBK * 4);
  int*      bbaseU= (int*)     alloc((size_t)NBK * 4);
  int*      curc2 = (int*)     alloc((size_t)N * 4);
  int*      curu2 = (int*)     alloc((size_t)N * 4);
  unsigned* pairC = (unsigned*)alloc((size_t)NBK * CAP * 4);   // aliased later as s2e
  uint2*    pairU = (uint2*)   alloc((size_t)NBK * CAP * 8);
  uint2*    adjc  = (uint2*)   alloc((size_t)NE * 8);
  uint2*    adju  = (uint2*)   alloc((size_t)NE * 8);
  unsigned* adj3c = (unsigned*)alloc((size_t)NT * 4);
  uint2*    adj3i = (uint2*)   alloc((size_t)NT * 2 * 8);
  float*    s3c   = (float*)   alloc((size_t)NT * 4);
  float2*   ml2   = (float2*)  alloc((size_t)N * 8);
  float2*   ml3   = (float2*)  alloc((size_t)N * 8);
  ushort_t* Kmb   = (ushort_t*)alloc((size_t)128 * 256 * 2);
  ushort_t* KWb   = (ushort_t*)alloc((size_t)256 * 128 * 2);
  float*    meanb = (float*)   alloc((size_t)N * 4);
  float*    rstdb = (float*)   alloc((size_t)N * 4);
  float*    lseM  = (float*)   alloc((size_t)N * 4);
  ushort_t* WtQm  = (ushort_t*)alloc(65536 * 2);
  ushort_t* WtF2  = (ushort_t*)alloc(131072 * 2);
  ushort_t* WtF3  = (ushort_t*)alloc(262144 * 2);
  ushort_t* WbQm  = (ushort_t*)alloc(65536 * 2);
  ushort_t* Bt2   = (ushort_t*)alloc(131072 * 2);
  ushort_t* Bt3   = (ushort_t*)alloc(262144 * 2);

  int* curc3 = zreg;
  int* curi3 = zreg + N;
  int* bcntC = zreg + 2 * N;
  int* bcntU = zreg + 2 * N + NBK;
  float* s2e = (float*)pairC;       // alias: pairC dead after passB2<0>
  float* out = (float*)d_out;
  float*    Sm = (float*)bufB;
  ushort_t* Pb = (ushort_t*)(Sm + (size_t)N * 128);

  zfill(zreg, (size_t)2 * N + 2 * NBK, stream);

  // 1. LN forward + weight prep
  ln_fwd<<<N, 256, 0, stream>>>(X, gamma, beta, Gb, meanb, rstdb);
  wprep_all<<<(917504 + 255) / 256, 256, 0, stream>>>(W_Q2, W_K2, W_Q3, W_K3, W_Qm,
      WtQm, WtF2, WtF3, WbQm, Bt2, Bt3);

  // CSR build: order-2 binned two-phase, order-3 old scheme
  passA2<<<(NE + 255) / 256, 256, 0, stream>>>(c2, u2, bcntC, bcntU, pairC, pairU, NE);
  hist3<<<(NT + 255) / 256, 256, 0, stream>>>(c3, u3, v3, curc3, curi3, NT);
  scan_mixed<<<4, 256, 0, stream>>>(bcntC, bbaseC, bcntU, bbaseU, curc3, NBK, N);
  passB2<0><<<NBK, 256, 0, stream>>>(bcntC, bbaseC, pairC, pairU, adjc, curc2);
  passB2<1><<<NBK, 256, 0, stream>>>(bcntU, bbaseU, pairC, pairU, adju, curu2);
  scatter3<<<(NT + 255) / 256, 256, 0, stream>>>(c3, u3, v3, tt, curc3, curi3, adj3c, adj3i, NT);

  dim3 g256(2, N / 128), g512(4, N / 128), g1024(8, N / 128);

  // 2. memory phase (GEMM-shaped)
  km_kernel<<<128, 256, 0, stream>>>(B_mem, W_Km, Kmb);
  gemm_bt_mfma<2><<<dim3(1, 2), 256, 0, stream>>>(WbQm, Kmb, KWb, 256, 128);
  gemm_bt_mfma<2><<<g256, 256, 0, stream>>>(Gb, WtQm, bufA, D_, D_);
  gemm_bt_mfma<0><<<dim3(1, N / 128), 256, 0, stream>>>(bufA, Kmb, Sm, 256, 128);
  softmax32<<<N / 8, 256, 0, stream>>>(Sm, Pb, lseM, bmp, lmp);
  gemm_bt_mfma<0><<<g256, 256, 0, stream>>>(Pb, KWb, out, 128, D_);

  // 3. order-2 phase
  gemm_bt_mfma<2><<<g512, 256, 0, stream>>>(Gb, WtF2, bufA, D_, 512);
  e2_rowc<<<N / 4, 256, 0, stream>>>(bufA, curc2, adjc, bufB, s2e, ml2, b2p, l2p);
  e2_rowu<<<N / 4, 256, 0, stream>>>(bufA, curu2, adju, s2e, ml2, bufB, l2p);
  gemm_bt_mfma<1><<<g256, 256, 0, stream>>>(bufB, Bt2, out, 512, D_);

  // 4. order-3 phase
  gemm_bt_mfma<2><<<g1024, 256, 0, stream>>>(Gb, WtF3, bufA, D_, 1024);
  e3_rowc<<<N / 4, 256, 0, stream>>>(bufA, T_tau, curc3, adj3c, bufB, s3c, ml3, b3p, l3p);
  e3_rowi<<<N / 4, 256, 0, stream>>>(bufA, T_tau, curi3, adj3i, s3c, ml3, bufB, l3p);
  gemm_bt_mfma<1><<<g256, 256, 0, stream>>>(bufB, Bt3, out, 1024, D_);

  // 5. LN backward + clips + update
  ln_bwd_update<<<N, 256, 0, stream>>>(X, out, gamma, meanb, rstdb, stepp, out);

  // 6. energy
  energy_final<<<1, 256, 0, stream>>>(ml2, ml3, lseM, N, l2p, l3p, lmp, b2p, b3p, bmp, out + ND);
}

// Round 8
// 952.939 us; speedup vs baseline: 1.2415x; 1.2415x over previous
//
#include <hip/hip_runtime.h>
#include <math.h>

#define D_ 256
#define KSLOT 32
#define CAP2 128      // order-2 slots per row (Poisson(30.5), 18 sigma)
#define CAP3C 16      // order-3 c-side slots per row (Poisson(2))
#define CAP3I 32      // order-3 incidence slots per row (Poisson(4))
typedef unsigned short ushort_t;
typedef __attribute__((ext_vector_type(8))) short bf16x8;
typedef __attribute__((ext_vector_type(4))) float f32x4;

// ---------- helpers ----------
__device__ __forceinline__ float softplus_f(float x){
  return (x > 20.0f) ? x : log1pf(expf(x));
}
__device__ __forceinline__ float bflo(unsigned u){ return __uint_as_float(u << 16); }
__device__ __forceinline__ float bfhi(unsigned u){ return __uint_as_float(u & 0xFFFF0000u); }
__device__ __forceinline__ ushort_t f2b(float f){
  unsigned u = __float_as_uint(f);
  unsigned r = u + 0x7FFFu + ((u >> 16) & 1u);
  return (ushort_t)(r >> 16);
}
__device__ __forceinline__ unsigned pack2(float a, float b){
  return (unsigned)f2b(a) | ((unsigned)f2b(b) << 16);
}
__device__ __forceinline__ void unpack16(uint4 a, uint4 b, float* f){
  f[0]=bflo(a.x); f[1]=bfhi(a.x); f[2]=bflo(a.y); f[3]=bfhi(a.y);
  f[4]=bflo(a.z); f[5]=bfhi(a.z); f[6]=bflo(a.w); f[7]=bfhi(a.w);
  f[8]=bflo(b.x); f[9]=bfhi(b.x); f[10]=bflo(b.y); f[11]=bfhi(b.y);
  f[12]=bflo(b.z); f[13]=bfhi(b.z); f[14]=bflo(b.w); f[15]=bfhi(b.w);
}
__device__ __forceinline__ float block_reduce_sum(float v, float* sbuf){
  #pragma unroll
  for (int o = 32; o > 0; o >>= 1) v += __shfl_xor(v, o);
  int t = threadIdx.x, wid = t >> 6, lane = t & 63;
  if (lane == 0) sbuf[wid] = v;
  __syncthreads();
  if (t == 0) sbuf[0] = sbuf[0] + sbuf[1] + sbuf[2] + sbuf[3];
  __syncthreads();
  float r = sbuf[0];
  __syncthreads();
  return r;
}

// ---------- zero fill ----------
__global__ __launch_bounds__(256) void zerok(float4* __restrict__ p, size_t n4){
  float4 z; z.x = z.y = z.z = z.w = 0.f;
  for (size_t i = (size_t)blockIdx.x * 256 + threadIdx.x; i < n4; i += (size_t)gridDim.x * 256)
    p[i] = z;
}

// ---------- layernorm forward -> bf16 G ----------
__global__ __launch_bounds__(256) void ln_fwd(const float* __restrict__ X, const float* __restrict__ gamma,
    const float* __restrict__ beta, ushort_t* __restrict__ Gb, float* __restrict__ mean, float* __restrict__ rstd)
{
  __shared__ float sbuf[8];
  int n = blockIdx.x, t = threadIdx.x;
  size_t idx = (size_t)n * D_ + t;
  float x = X[idx];
  float mu = block_reduce_sum(x, sbuf) * (1.0f / D_);
  float d = x - mu;
  float var = block_reduce_sum(d * d, sbuf) * (1.0f / D_);
  float rs = rsqrtf(var + 1e-5f);
  Gb[idx] = f2b(d * rs * gamma[t] + beta[t]);
  if (t == 0){ mean[n] = mu; rstd[n] = rs; }
}

// ---------- fused weight prep ----------
__global__ __launch_bounds__(256) void wprep_all(const float* __restrict__ W_Q2, const float* __restrict__ W_K2,
    const float* __restrict__ W_Q3, const float* __restrict__ W_K3, const float* __restrict__ W_Qm,
    ushort_t* __restrict__ WtQm, ushort_t* __restrict__ WtF2, ushort_t* __restrict__ WtF3,
    ushort_t* __restrict__ WbQm, ushort_t* __restrict__ Bt2, ushort_t* __restrict__ Bt3)
{
  int idx = blockIdx.x * 256 + threadIdx.x;
  if (idx < 65536){
    int m = idx >> 8, k = idx & 255;
    WtQm[idx] = f2b(W_Qm[k * 256 + m]);
    return;
  }
  idx -= 65536;
  if (idx < 131072){
    int m = idx >> 8, k = idx & 255;
    WtF2[idx] = f2b(m < 256 ? W_Q2[k * 256 + m] : W_K2[k * 256 + (m - 256)]);
    return;
  }
  idx -= 131072;
  if (idx < 262144){
    int m = idx >> 8, k = idx & 255;
    WtF3[idx] = f2b(m < 512 ? W_Q3[k * 512 + m] : W_K3[k * 512 + (m - 512)]);
    return;
  }
  idx -= 262144;
  if (idx < 65536){ WbQm[idx] = f2b(W_Qm[idx]); return; }
  idx -= 65536;
  if (idx < 131072){
    int d = idx >> 9, k = idx & 511;
    Bt2[idx] = f2b(k < 256 ? W_Q2[d * 256 + k] : W_K2[d * 256 + (k - 256)]);
    return;
  }
  idx -= 131072;
  if (idx < 262144){
    int d = idx >> 10, k = idx & 1023;
    Bt3[idx] = f2b(k < 512 ? W_Q3[d * 512 + k] : W_K3[d * 512 + (k - 512)]);
  }
}

// ---------- MFMA GEMM with async global->LDS staging: C[N,M] op= A[N,K] @ Bt[M,K]^T ----------
template<int OUT_MODE>  // 0 store fp32, 1 accumulate fp32, 2 store bf16
__global__ __launch_bounds__(256) void gemm_bt_mfma(const ushort_t* __restrict__ A,
    const ushort_t* __restrict__ Bt, void* __restrict__ C, int K, int M)
{
  __shared__ __align__(16) ushort_t As[128 * 32];
  __shared__ __align__(16) ushort_t Bs[128 * 32];
  int t = threadIdx.x;
  int wave = t >> 6, lane = t & 63;
  int row0 = blockIdx.y * 128;
  int col0 = blockIdx.x * 128;
  int wrow = (wave & 1) * 64;
  int wcol = (wave >> 1) * 64;
  f32x4 acc[4][4];
  #pragma unroll
  for (int i = 0; i < 4; ++i)
    #pragma unroll
    for (int j = 0; j < 4; ++j)
      acc[i][j] = (f32x4){0.f, 0.f, 0.f, 0.f};
  // async-staging mapping: wave w, call c, lane l -> LDS byte w*2048 + c*1024 + l*16
  //   = row (w*32 + c*16 + (l>>2)), elem (l&3)*8   [rows 32 ushort wide]
  int srow = wave * 32 + (lane >> 2);
  int skoff = (lane & 3) * 8;
  const ushort_t* Ag0 = A + (size_t)(row0 + srow) * K + skoff;
  const ushort_t* Ag1 = A + (size_t)(row0 + srow + 16) * K + skoff;
  const ushort_t* Bg0 = Bt + (size_t)(col0 + srow) * K + skoff;
  const ushort_t* Bg1 = Bt + (size_t)(col0 + srow + 16) * K + skoff;
  ushort_t* Al0 = As + wave * 1024;          // wave-uniform LDS bases
  ushort_t* Al1 = As + wave * 1024 + 512;
  ushort_t* Bl0 = Bs + wave * 1024;
  ushort_t* Bl1 = Bs + wave * 1024 + 512;
  int lrow = lane & 15, lk = (lane >> 4) * 8;
  for (int k0 = 0; k0 < K; k0 += 32){
    __syncthreads();
    __builtin_amdgcn_global_load_lds((const __attribute__((address_space(1))) void*)(Ag0 + k0),
                                     (__attribute__((address_space(3))) void*)Al0, 16, 0, 0);
    __builtin_amdgcn_global_load_lds((const __attribute__((address_space(1))) void*)(Ag1 + k0),
                                     (__attribute__((address_space(3))) void*)Al1, 16, 0, 0);
    __builtin_amdgcn_global_load_lds((const __attribute__((address_space(1))) void*)(Bg0 + k0),
                                     (__attribute__((address_space(3))) void*)Bl0, 16, 0, 0);
    __builtin_amdgcn_global_load_lds((const __attribute__((address_space(1))) void*)(Bg1 + k0),
                                     (__attribute__((address_space(3))) void*)Bl1, 16, 0, 0);
    __syncthreads();
    bf16x8 af[4], bf_[4];
    #pragma unroll
    for (int i = 0; i < 4; ++i)
      af[i] = *(const bf16x8*)(As + (wrow + i * 16 + lrow) * 32 + lk);
    #pragma unroll
    for (int j = 0; j < 4; ++j)
      bf_[j] = *(const bf16x8*)(Bs + (wcol + j * 16 + lrow) * 32 + lk);
    #pragma unroll
    for (int i = 0; i < 4; ++i)
      #pragma unroll
      for (int j = 0; j < 4; ++j)
        acc[i][j] = __builtin_amdgcn_mfma_f32_16x16x32_bf16(af[i], bf_[j], acc[i][j], 0, 0, 0);
  }
  int rbase = row0 + wrow + (lane >> 4) * 4;
  int cbase = col0 + wcol + (lane & 15);
  #pragma unroll
  for (int i = 0; i < 4; ++i){
    #pragma unroll
    for (int r = 0; r < 4; ++r){
      size_t rowoff = (size_t)(rbase + i * 16 + r) * M;
      #pragma unroll
      for (int j = 0; j < 4; ++j){
        int col = cbase + j * 16;
        float v = acc[i][j][r];
        if (OUT_MODE == 0)      ((float*)C)[rowoff + col] = v;
        else if (OUT_MODE == 1) ((float*)C)[rowoff + col] += v;
        else                    ((ushort_t*)C)[rowoff + col] = f2b(v);
      }
    }
  }
}

// ---------- Km = B_mem @ W_Km -> bf16 padded [128,256] (rows >=32 zeroed) ----------
__global__ __launch_bounds__(256) void km_kernel(const float* __restrict__ Bm, const float* __restrict__ W,
    ushort_t* __restrict__ Kmb)
{
  __shared__ float sb[D_];
  int k = blockIdx.x, t = threadIdx.x;
  if (k < KSLOT){
    sb[t] = Bm[(size_t)k * D_ + t];
    __syncthreads();
    float acc = 0.f;
    for (int d = 0; d < D_; ++d) acc += sb[d] * W[(size_t)d * D_ + t];
    Kmb[(size_t)k * D_ + t] = f2b(acc);
  } else {
    Kmb[(size_t)k * D_ + t] = 0;
  }
}

// ---------- mem softmax ----------
__global__ __launch_bounds__(256) void softmax32(const float* __restrict__ Sm, ushort_t* __restrict__ Pb,
    float* __restrict__ lseM, const float* __restrict__ bmp, const float* __restrict__ lmp)
{
  int t = threadIdx.x;
  int r = blockIdx.x * 8 + (t >> 5);
  int lane = t & 31;
  float bs = fminf(softplus_f(*bmp), 5.0f) * 0.0625f;
  float coef = -softplus_f(*lmp) * 0.0625f;
  float s = Sm[(size_t)r * 128 + lane] * bs;
  float m = s;
  #pragma unroll
  for (int o = 16; o > 0; o >>= 1) m = fmaxf(m, __shfl_xor(m, o, 32));
  float e = expf(s - m);
  float se = e;
  #pragma unroll
  for (int o = 16; o > 0; o >>= 1) se += __shfl_xor(se, o, 32);
  ushort_t* dst = Pb + (size_t)r * 128 + lane;
  dst[0] = f2b(coef * e / se);
  dst[32] = 0; dst[64] = 0; dst[96] = 0;
  if (lane == 0) lseM[r] = m + logf(se);
}

// ---------- order-2: single-pass fixed-cap scatter ----------
__global__ __launch_bounds__(256) void scatter2(const int* __restrict__ c2, const int* __restrict__ u2,
    int* __restrict__ cntC, int* __restrict__ cntU, int* __restrict__ adjc, int* __restrict__ adju, int NE_)
{
  int e = blockIdx.x * 256 + threadIdx.x;
  if (e >= NE_) return;
  int c = c2[e], u = u2[e];
  int pc = atomicAdd(cntC + c, 1);
  int gs = (c << 7) + pc;
  bool okc = (pc < CAP2);
  if (okc) adjc[gs] = u;
  int pu = atomicAdd(cntU + u, 1);
  if (pu < CAP2 && okc) adju[(u << 7) + pu] = gs;
}

// ---------- order-3: single-pass fixed-cap scatter ----------
__global__ __launch_bounds__(256) void scatter3(const int* __restrict__ c3, const int* __restrict__ u3,
    const int* __restrict__ v3, const int* __restrict__ tt, int* __restrict__ cnt3C, int* __restrict__ cnt3I,
    unsigned* __restrict__ adj3c, uint2* __restrict__ adj3i, int NT_)
{
  int e = blockIdx.x * 256 + threadIdx.x;
  if (e >= NT_) return;
  int c = c3[e], u = u3[e], v = v3[e], tau = tt[e];
  int pc = atomicAdd(cnt3C + c, 1);
  if (pc >= CAP3C) return;
  int cslot = (c << 4) + pc;
  adj3c[cslot] = (unsigned)u | ((unsigned)v << 15) | ((unsigned)tau << 30);
  int pu = atomicAdd(cnt3I + u, 1);
  if (pu < CAP3I){
    uint2 eu; eu.x = (unsigned)c | ((unsigned)tau << 15) | ((unsigned)v << 16); eu.y = (unsigned)cslot;
    adj3i[(u << 5) + pu] = eu;
  }
  int pv = atomicAdd(cnt3I + v, 1);
  if (pv < CAP3I){
    uint2 ev; ev.x = (unsigned)c | ((unsigned)tau << 15) | ((unsigned)u << 16); ev.y = (unsigned)cslot;
    adj3i[(v << 5) + pv] = ev;
  }
}

// ---------- order-2 by-c: 16 lanes/edge, online softmax + dQ2 ----------
__global__ __launch_bounds__(256) void e2_rowc(const ushort_t* __restrict__ QK2, const int* __restrict__ cntC,
    const int* __restrict__ adjc, ushort_t* __restrict__ dstage, float* __restrict__ s2e,
    float2* __restrict__ ml2, const float* __restrict__ b2p, const float* __restrict__ l2p)
{
  int wave = threadIdx.x >> 6, lane = threadIdx.x & 63;
  int r = blockIdx.x * 4 + wave;
  int quarter = lane >> 4, sub = lane & 15;
  float b2s = fminf(softplus_f(*b2p), 5.0f) * 0.0625f;
  float lam2 = softplus_f(*l2p);
  int start = r << 7;
  int deg = cntC[r]; if (deg > CAP2) deg = CAP2;
  int end = start + deg;
  const ushort_t* qrow = QK2 + (size_t)r * 512 + sub * 16;
  float qf[16];
  unpack16(*(const uint4*)qrow, *(const uint4*)(qrow + 8), qf);
  float m = -1e30f, l = 0.f;
  float a[16] = {};
  for (int p = start + quarter; p < end; p += 4){
    int u = adjc[p];
    const ushort_t* krow = QK2 + (size_t)u * 512 + 256 + sub * 16;
    float kf[16];
    unpack16(*(const uint4*)krow, *(const uint4*)(krow + 8), kf);
    float d = 0.f;
    #pragma unroll
    for (int j = 0; j < 16; ++j) d += qf[j] * kf[j];
    d += __shfl_xor(d, 1); d += __shfl_xor(d, 2); d += __shfl_xor(d, 4); d += __shfl_xor(d, 8);
    float s = d * b2s;
    if (sub == 0) s2e[p] = s;
    float mn = fmaxf(m, s);
    float sc = expf(m - mn);
    float pt = expf(s - mn);
    l = l * sc + pt;
    #pragma unroll
    for (int j = 0; j < 16; ++j) a[j] = a[j] * sc + pt * kf[j];
    m = mn;
  }
  float M = fmaxf(m, __shfl_xor(m, 16)); M = fmaxf(M, __shfl_xor(M, 32));
  float scq = expf(m - M);
  float L = l * scq;
  L += __shfl_xor(L, 16); L += __shfl_xor(L, 32);
  #pragma unroll
  for (int j = 0; j < 16; ++j){
    float x = a[j] * scq;
    x += __shfl_xor(x, 16); x += __shfl_xor(x, 32);
    a[j] = x;
  }
  float linv = 0.f, coef = 0.f;
  if (deg > 0){ linv = 1.0f / L; coef = -lam2 * 0.0625f * linv; }
  if (lane == 0){
    float2 ml; ml.x = M; ml.y = linv;
    ml2[r] = ml;
  }
  if (quarter == 0){
    ushort_t* dst = dstage + (size_t)r * 512 + sub * 16;
    uint4 p0, p1;
    p0.x = pack2(coef*a[0], coef*a[1]);   p0.y = pack2(coef*a[2], coef*a[3]);
    p0.z = pack2(coef*a[4], coef*a[5]);   p0.w = pack2(coef*a[6], coef*a[7]);
    p1.x = pack2(coef*a[8], coef*a[9]);   p1.y = pack2(coef*a[10], coef*a[11]);
    p1.z = pack2(coef*a[12], coef*a[13]); p1.w = pack2(coef*a[14], coef*a[15]);
    *(uint4*)dst = p0; *(uint4*)(dst + 8) = p1;
  }
}

// ---------- order-2 by-u: stored scores via gslot, dK2 ----------
__global__ __launch_bounds__(256) void e2_rowu(const ushort_t* __restrict__ QK2, const int* __restrict__ cntU,
    const int* __restrict__ adju, const float* __restrict__ s2e, const float2* __restrict__ ml2,
    ushort_t* __restrict__ dstage, const float* __restrict__ l2p)
{
  int wave = threadIdx.x >> 6, lane = threadIdx.x & 63;
  int r = blockIdx.x * 4 + wave;
  int quarter = lane >> 4, sub = lane & 15;
  float lam2 = softplus_f(*l2p);
  int start = r << 7;
  int deg = cntU[r]; if (deg > CAP2) deg = CAP2;
  int end = start + deg;
  float a[16] = {};
  for (int p = start + quarter; p < end; p += 4){
    int gs = adju[p];
    int c = gs >> 7;
    float2 ml = ml2[c];
    float pe = expf(s2e[gs] - ml.x) * ml.y;
    const ushort_t* qrow = QK2 + (size_t)c * 512 + sub * 16;
    float qf[16];
    unpack16(*(const uint4*)qrow, *(const uint4*)(qrow + 8), qf);
    #pragma unroll
    for (int j = 0; j < 16; ++j) a[j] += pe * qf[j];
  }
  #pragma unroll
  for (int j = 0; j < 16; ++j){
    float x = a[j];
    x += __shfl_xor(x, 16); x += __shfl_xor(x, 32);
    a[j] = x;
  }
  float coef = -lam2 * 0.0625f;
  if (quarter == 0){
    ushort_t* dst = dstage + (size_t)r * 512 + 256 + sub * 16;
    uint4 p0, p1;
    p0.x = pack2(coef*a[0], coef*a[1]);   p0.y = pack2(coef*a[2], coef*a[3]);
    p0.z = pack2(coef*a[4], coef*a[5]);   p0.w = pack2(coef*a[6], coef*a[7]);
    p1.x = pack2(coef*a[8], coef*a[9]);   p1.y = pack2(coef*a[10], coef*a[11]);
    p1.z = pack2(coef*a[12], coef*a[13]); p1.w = pack2(coef*a[14], coef*a[15]);
    *(uint4*)dst = p0; *(uint4*)(dst + 8) = p1;
  }
}

// ---------- order-3 by-c: online softmax + dQ3, wave per row, T in LDS ----------
__global__ __launch_bounds__(256) void e3_rowc(const ushort_t* __restrict__ QK3, const float* __restrict__ Tt,
    const int* __restrict__ cnt3C, const unsigned* __restrict__ adj3c, ushort_t* __restrict__ dstage,
    float* __restrict__ s3c, float2* __restrict__ ml3, const float* __restrict__ b3p,
    const float* __restrict__ l3p)
{
  __shared__ float sT[1024];
  int wave = threadIdx.x >> 6, lane = threadIdx.x & 63;
  int r = blockIdx.x * 4 + wave;
  for (int i = threadIdx.x; i < 1024; i += 256) sT[i] = Tt[i];
  __syncthreads();
  float b3s = fminf(softplus_f(*b3p), 5.0f) * 0.0625f;
  float lam3 = softplus_f(*l3p);
  int start = r << 4;
  int deg = cnt3C[r]; if (deg > CAP3C) deg = CAP3C;
  int end = start + deg;
  uint4 qw = *(const uint4*)(QK3 + (size_t)r * 1024 + lane * 8);
  float q[8] = {bflo(qw.x),bfhi(qw.x),bflo(qw.y),bfhi(qw.y),bflo(qw.z),bfhi(qw.z),bflo(qw.w),bfhi(qw.w)};
  float T0[8], T1[8];
  #pragma unroll
  for (int j = 0; j < 8; ++j){ T0[j] = sT[lane * 8 + j]; T1[j] = sT[512 + lane * 8 + j]; }
  float m = -1e30f, l = 0.f;
  float a[8] = {};
  for (int p = start; p < end; ++p){
    unsigned ent = adj3c[p];
    int u = ent & 32767, v = (ent >> 15) & 32767, tau = (ent >> 30) & 1;
    uint4 bw = *(const uint4*)(QK3 + (size_t)u * 1024 + 512 + lane * 8);
    uint4 cw = *(const uint4*)(QK3 + (size_t)v * 1024 + 512 + lane * 8);
    float kb[8] = {bflo(bw.x),bfhi(bw.x),bflo(bw.y),bfhi(bw.y),bflo(bw.z),bfhi(bw.z),bflo(bw.w),bfhi(bw.w)};
    float kc[8] = {bflo(cw.x),bfhi(cw.x),bflo(cw.y),bfhi(cw.y),bflo(cw.z),bfhi(cw.z),bflo(cw.w),bfhi(cw.w)};
    float prod[8];
    float d = 0.f;
    #pragma unroll
    for (int j = 0; j < 8; ++j){
      float tj = tau ? T1[j] : T0[j];
      prod[j] = kb[j] * kc[j] * tj;
      d += q[j] * prod[j];
    }
    #pragma unroll
    for (int o = 32; o > 0; o >>= 1) d += __shfl_xor(d, o);
    float s = d * b3s;
    if (lane == 0) s3c[p] = s;
    float mn = fmaxf(m, s);
    float sc = expf(m - mn);
    float pt = expf(s - mn);
    l = l * sc + pt;
    #pragma unroll
    for (int j = 0; j < 8; ++j) a[j] = a[j]*sc + pt*prod[j];
    m = mn;
  }
  float linv = 0.f, coef = 0.f;
  if (deg > 0){ linv = 1.0f / l; coef = -lam3 * 0.0625f * linv; }
  uint4 o4;
  o4.x = pack2(coef*a[0], coef*a[1]); o4.y = pack2(coef*a[2], coef*a[3]);
  o4.z = pack2(coef*a[4], coef*a[5]); o4.w = pack2(coef*a[6], coef*a[7]);
  *(uint4*)(dstage + (size_t)r * 1024 + lane * 8) = o4;
  if (lane == 0){
    float2 ml; ml.x = m; ml.y = linv;
    ml3[r] = ml;
  }
}

// ---------- order-3 incidence: stored scores, dK3, T in LDS ----------
__global__ __launch_bounds__(256) void e3_rowi(const ushort_t* __restrict__ QK3, const float* __restrict__ Tt,
    const int* __restrict__ cnt3I, const uint2* __restrict__ adj3i, const float* __restrict__ s3c,
    const float2* __restrict__ ml3, ushort_t* __restrict__ dstage, const float* __restrict__ l3p)
{
  __shared__ float sT[1024];
  int wave = threadIdx.x >> 6, lane = threadIdx.x & 63;
  int r = blockIdx.x * 4 + wave;
  for (int i = threadIdx.x; i < 1024; i += 256) sT[i] = Tt[i];
  __syncthreads();
  float lam3 = softplus_f(*l3p);
  int start = r << 5;
  int deg = cnt3I[r]; if (deg > CAP3I) deg = CAP3I;
  int end = start + deg;
  float T0[8], T1[8];
  #pragma unroll
  for (int j = 0; j < 8; ++j){ T0[j] = sT[lane * 8 + j]; T1[j] = sT[512 + lane * 8 + j]; }
  float a[8] = {};
  for (int p = start; p < end; ++p){
    uint2 ent = adj3i[p];
    int c = ent.x & 32767, tau = (ent.x >> 15) & 1, other = (ent.x >> 16) & 32767;
    float2 ml = ml3[c];
    float pe = expf(s3c[ent.y] - ml.x) * ml.y;
    uint4 qw = *(const uint4*)(QK3 + (size_t)c * 1024 + lane * 8);
    uint4 ow = *(const uint4*)(QK3 + (size_t)other * 1024 + 512 + lane * 8);
    float q[8] = {bflo(qw.x),bfhi(qw.x),bflo(qw.y),bfhi(qw.y),bflo(qw.z),bfhi(qw.z),bflo(qw.w),bfhi(qw.w)};
    float ko[8] = {bflo(ow.x),bfhi(ow.x),bflo(ow.y),bfhi(ow.y),bflo(ow.z),bfhi(ow.z),bflo(ow.w),bfhi(ow.w)};
    #pragma unroll
    for (int j = 0; j < 8; ++j){
      float tj = tau ? T1[j] : T0[j];
      a[j] += pe * q[j] * ko[j] * tj;
    }
  }
  float coef = -lam3 * 0.0625f;
  uint4 o4;
  o4.x = pack2(coef*a[0], coef*a[1]); o4.y = pack2(coef*a[2], coef*a[3]);
  o4.z = pack2(coef*a[4], coef*a[5]); o4.w = pack2(coef*a[6], coef*a[7]);
  *(uint4*)(dstage + (size_t)r * 1024 + 512 + lane * 8) = o4;
}

// ---------- LN backward + clips + update ----------
__global__ __launch_bounds__(256) void ln_bwd_update(const float* __restrict__ X, const float* __restrict__ dG,
    const float* __restrict__ gamma, const float* __restrict__ mean, const float* __restrict__ rstd,
    const float* __restrict__ step_p, float* __restrict__ out)
{
  __shared__ float sbuf[8];
  int n = blockIdx.x, t = threadIdx.x;
  size_t idx = (size_t)n * D_ + t;
  float x = X[idx];
  float rs = rstd[n];
  float xh = (x - mean[n]) * rs;
  float dxh = dG[idx] * gamma[t];
  float s1 = block_reduce_sum(dxh, sbuf) * (1.0f / D_);
  float s2v = block_reduce_sum(dxh * xh, sbuf) * (1.0f / D_);
  float dx = rs * (dxh - s1 - xh * s2v);
  float gn2 = block_reduce_sum(dx * dx, sbuf);
  float gn = fmaxf(sqrtf(gn2), 1e-6f);
  float gsc = fminf(1.0f / gn, 1.0f);
  float stp = step_p[0] * 0.9999f;
  float xn = x - stp * gsc * dx;
  float sn2 = block_reduce_sum(xn * xn, sbuf);
  float sn = fmaxf(sqrtf(sn2), 1e-6f);
  float ssc = fminf(10.0f / sn, 1.0f);
  out[idx] = xn * ssc;
}

// ---------- single-block: all three energy sums + final combine ----------
__global__ __launch_bounds__(256) void energy_final(const float2* __restrict__ ml2, const float2* __restrict__ ml3,
    const float* __restrict__ lseM, int n, const float* l2p, const float* l3p, const float* lmp,
    const float* b2p, const float* b3p, const float* bmp, float* __restrict__ outE)
{
  __shared__ float sbuf[8];
  int t = threadIdx.x;
  float a2 = 0.f, a3 = 0.f, am = 0.f;
  for (int i = t; i < n; i += 256){
    float2 v2 = ml2[i];
    if (v2.y > 0.f) a2 += v2.x - logf(v2.y);
    float2 v3 = ml3[i];
    if (v3.y > 0.f) a3 += v3.x - logf(v3.y);
    am += lseM[i];
  }
  float s2 = block_reduce_sum(a2, sbuf);
  float s3 = block_reduce_sum(a3, sbuf);
  float sm = block_reduce_sum(am, sbuf);
  if (t == 0){
    float l2 = softplus_f(*l2p), l3 = softplus_f(*l3p), lm = softplus_f(*lmp);
    float b2 = fminf(softplus_f(*b2p), 5.0f);
    float b3 = fminf(softplus_f(*b3p), 5.0f);
    float bm = fminf(softplus_f(*bmp), 5.0f);
    *outE = -(l2 / b2) * s2 - (l3 / b3) * s3 - (lm / bm) * sm;
  }
}

static inline void zfill(void* p, size_t nElems, hipStream_t stream){
  size_t n4 = nElems / 4;
  int blocks = (int)(((n4 + 255) / 256) < 16384 ? ((n4 + 255) / 256) : 16384);
  if (blocks < 1) blocks = 1;
  zerok<<<blocks, 256, 0, stream>>>((float4*)p, n4);
}

extern "C" void kernel_launch(void* const* d_in, const int* in_sizes, int n_in,
                              void* d_out, int out_size, void* d_ws, size_t ws_size,
                              hipStream_t stream)
{
  const float* X     = (const float*)d_in[0];
  const int*   c2    = (const int*)d_in[1];
  const int*   u2    = (const int*)d_in[2];
  const int*   c3    = (const int*)d_in[3];
  const int*   u3    = (const int*)d_in[4];
  const int*   v3    = (const int*)d_in[5];
  const int*   tt    = (const int*)d_in[6];
  const float* stepp = (const float*)d_in[7];
  const float* gamma = (const float*)d_in[8];
  const float* beta  = (const float*)d_in[9];
  const float* W_Q2  = (const float*)d_in[10];
  const float* W_K2  = (const float*)d_in[11];
  const float* W_Q3  = (const float*)d_in[12];
  const float* W_K3  = (const float*)d_in[13];
  const float* T_tau = (const float*)d_in[14];
  const float* W_Qm  = (const float*)d_in[15];
  const float* W_Km  = (const float*)d_in[16];
  const float* B_mem = (const float*)d_in[17];
  const float* l2p   = (const float*)d_in[18];
  const float* l3p   = (const float*)d_in[19];
  const float* lmp   = (const float*)d_in[20];
  const float* b2p   = (const float*)d_in[21];
  const float* b3p   = (const float*)d_in[22];
  const float* bmp   = (const float*)d_in[23];

  const int N  = in_sizes[0] / D_;
  const int NE = in_sizes[1];
  const int NT = in_sizes[3];
  const size_t ND = (size_t)N * D_;

  // ---- byte arena (~191 MB) ----
  char* base = (char*)d_ws;
  size_t off = 0;
  auto alloc = [&](size_t bytes) -> void* {
    void* p = base + off;
    off += (bytes + 255) & ~(size_t)255;
    return p;
  };
  ushort_t* Gb    = (ushort_t*)alloc(ND * 2);                    // 16 MB
  ushort_t* bufA  = (ushort_t*)alloc(ND * 4 * 2);                // 64 MB
  ushort_t* bufB  = (ushort_t*)alloc(ND * 4 * 2);                // 64 MB (o2: dstage 32MB | s2e 16MB)
  int*      zreg  = (int*)     alloc((size_t)4 * N * 4);         // cntC|cntU|cnt3C|cnt3I
  int*      adjc  = (int*)     alloc((size_t)N * CAP2 * 4);      // 16 MB
  int*      adju  = (int*)     alloc((size_t)N * CAP2 * 4);      // 16 MB
  unsigned* adj3c = (unsigned*)alloc((size_t)N * CAP3C * 4);     // 2 MB
  uint2*    adj3i = (uint2*)   alloc((size_t)N * CAP3I * 8);     // 8 MB
  float*    s3c   = (float*)   alloc((size_t)N * CAP3C * 4);     // 2 MB
  float2*   ml2   = (float2*)  alloc((size_t)N * 8);
  float2*   ml3   = (float2*)  alloc((size_t)N * 8);
  ushort_t* Kmb   = (ushort_t*)alloc((size_t)128 * 256 * 2);
  ushort_t* KWb   = (ushort_t*)alloc((size_t)256 * 128 * 2);
  float*    meanb = (float*)   alloc((size_t)N * 4);
  float*    rstdb = (float*)   alloc((size_t)N * 4);
  float*    lseM  = (float*)   alloc((size_t)N * 4);
  ushort_t* WtQm  = (ushort_t*)alloc(65536 * 2);
  ushort_t* WtF2  = (ushort_t*)alloc(131072 * 2);
  ushort_t* WtF3  = (ushort_t*)alloc(262144 * 2);
  ushort_t* WbQm  = (ushort_t*)alloc(65536 * 2);
  ushort_t* Bt2   = (ushort_t*)alloc(131072 * 2);
  ushort_t* Bt3   = (ushort_t*)alloc(262144 * 2);

  int* cntC  = zreg;
  int* cntU  = zreg + N;
  int* cnt3C = zreg + 2 * N;
  int* cnt3I = zreg + 3 * N;
  float* out = (float*)d_out;
  float*    Sm  = (float*)bufB;                          // mem phase
  ushort_t* Pb  = (ushort_t*)(Sm + (size_t)N * 128);
  float*    s2e = (float*)(bufB + ND * 2);               // o2 phase: upper 32MB of bufB

  zfill(zreg, (size_t)4 * N, stream);

  // 1. LN forward + weight prep
  ln_fwd<<<N, 256, 0, stream>>>(X, gamma, beta, Gb, meanb, rstdb);
  wprep_all<<<(917504 + 255) / 256, 256, 0, stream>>>(W_Q2, W_K2, W_Q3, W_K3, W_Qm,
      WtQm, WtF2, WtF3, WbQm, Bt2, Bt3);

  // CSR build: single-pass fixed-cap scatters (no hist, no scan, no pass B)
  scatter2<<<(NE + 255) / 256, 256, 0, stream>>>(c2, u2, cntC, cntU, adjc, adju, NE);
  scatter3<<<(NT + 255) / 256, 256, 0, stream>>>(c3, u3, v3, tt, cnt3C, cnt3I, adj3c, adj3i, NT);

  dim3 g256(2, N / 128), g512(4, N / 128), g1024(8, N / 128);

  // 2. memory phase (GEMM-shaped)
  km_kernel<<<128, 256, 0, stream>>>(B_mem, W_Km, Kmb);
  gemm_bt_mfma<2><<<dim3(1, 2), 256, 0, stream>>>(WbQm, Kmb, KWb, 256, 128);
  gemm_bt_mfma<2><<<g256, 256, 0, stream>>>(Gb, WtQm, bufA, D_, D_);
  gemm_bt_mfma<0><<<dim3(1, N / 128), 256, 0, stream>>>(bufA, Kmb, Sm, 256, 128);
  softmax32<<<N / 8, 256, 0, stream>>>(Sm, Pb, lseM, bmp, lmp);
  gemm_bt_mfma<0><<<g256, 256, 0, stream>>>(Pb, KWb, out, 128, D_);

  // 3. order-2 phase
  gemm_bt_mfma<2><<<g512, 256, 0, stream>>>(Gb, WtF2, bufA, D_, 512);
  e2_rowc<<<N / 4, 256, 0, stream>>>(bufA, cntC, adjc, bufB, s2e, ml2, b2p, l2p);
  e2_rowu<<<N / 4, 256, 0, stream>>>(bufA, cntU, adju, s2e, ml2, bufB, l2p);
  gemm_bt_mfma<1><<<g256, 256, 0, stream>>>(bufB, Bt2, out, 512, D_);

  // 4. order-3 phase
  gemm_bt_mfma<2><<<g1024, 256, 0, stream>>>(Gb, WtF3, bufA, D_, 1024);
  e3_rowc<<<N / 4, 256, 0, stream>>>(bufA, T_tau, cnt3C, adj3c, bufB, s3c, ml3, b3p, l3p);
  e3_rowi<<<N / 4, 256, 0, stream>>>(bufA, T_tau, cnt3I, adj3i, s3c, ml3, bufB, l3p);
  gemm_bt_mfma<1><<<g256, 256, 0, stream>>>(bufB, Bt3, out, 1024, D_);

  // 5. LN backward + clips + update
  ln_bwd_update<<<N, 256, 0, stream>>>(X, out, gamma, meanb, rstdb, stepp, out);

  // 6. energy
  energy_final<<<1, 256, 0, stream>>>(ml2, ml3, lseM, N, l2p, l3p, lmp, b2p, b3p, bmp, out + ND);
}